// Round 1
// baseline (71.798 us; speedup 1.0000x reference)
//
#include <hip/hip_runtime.h>

// Problem: ChamferDistance  B=16, N=M=4096, D=3, fp32 in/out (scalar out).
#define BQ     16
#define NPTS   4096
#define TOTAL  (BQ * NPTS)        // 65536 points per side
#define BLOCK  256
#define APT    4                  // a-points per thread (in registers)
#define ATILE  (BLOCK * APT)      // 1024 a-points per block
#define MTILE  512                // b-points staged in LDS per block
#define MT     (NPTS / MTILE)     // 8 m-tiles
#define ATILES (TOTAL / ATILE)    // 64 a-tiles

// ws layout: ws[0 .. 2*TOTAL) : uint32 bit-pattern of per-point min distance
//   [0, TOTAL)        -> dir 0 (min over points2 for each point1)
//   [TOTAL, 2*TOTAL)  -> dir 1 (min over points1 for each point2)

__global__ __launch_bounds__(BLOCK) void cd_init_ws(unsigned int* __restrict__ ws) {
    int i = blockIdx.x * BLOCK + threadIdx.x;
    ws[i] = 0x7F800000u;  // +inf
}

__global__ __launch_bounds__(BLOCK) void cd_min_kernel(
        const float* __restrict__ p1, const float* __restrict__ p2,
        unsigned int* __restrict__ wsmin) {
    const int dir = blockIdx.y;
    const float* __restrict__ Aset = dir ? p2 : p1;   // side we keep in registers
    const float* __restrict__ Bset = dir ? p1 : p2;   // side we scan from LDS
    unsigned int* __restrict__ outmin = wsmin + dir * TOTAL;

    const int atile = blockIdx.x / MT;
    const int mtile = blockIdx.x % MT;
    const int a0    = atile * ATILE;            // flat a-point base (never crosses batch: 4096%1024==0)
    const int batch = a0 / NPTS;
    const int m0    = batch * NPTS + mtile * MTILE;

    // Stage b-tile as (-2bx, -2by, -2bz, |b|^2): d = fma(az,bz', fma(ay,by', fma(ax,bx', a2+b2)))
    __shared__ float4 sb[MTILE];
    for (int i = threadIdx.x; i < MTILE; i += BLOCK) {
        const float* bp = Bset + (size_t)(m0 + i) * 3;
        float bx = bp[0], by = bp[1], bz = bp[2];
        sb[i] = make_float4(-2.0f * bx, -2.0f * by, -2.0f * bz,
                            fmaf(bx, bx, fmaf(by, by, bz * bz)));
    }
    __syncthreads();

    // Per-thread register a-points (strided so global loads coalesce per wave)
    float ax[APT], ay[APT], az[APT], a2[APT], mn[APT];
#pragma unroll
    for (int k = 0; k < APT; ++k) {
        const int ai = a0 + k * BLOCK + threadIdx.x;
        const float* ap = Aset + (size_t)ai * 3;
        ax[k] = ap[0]; ay[k] = ap[1]; az[k] = ap[2];
        a2[k] = fmaf(ax[k], ax[k], fmaf(ay[k], ay[k], az[k] * az[k]));
        mn[k] = 3.0e38f;
    }

    // Main loop: broadcast LDS reads (all lanes same addr -> conflict-free),
    // 2 b-points per step so fminf(fminf(d0,d1), mn) can fuse to v_min3_f32.
#pragma unroll 4
    for (int j = 0; j < MTILE; j += 2) {
        const float4 b0 = sb[j];
        const float4 b1 = sb[j + 1];
#pragma unroll
        for (int k = 0; k < APT; ++k) {
            float d0 = a2[k] + b0.w;
            d0 = fmaf(ax[k], b0.x, d0);
            d0 = fmaf(ay[k], b0.y, d0);
            d0 = fmaf(az[k], b0.z, d0);
            float d1 = a2[k] + b1.w;
            d1 = fmaf(ax[k], b1.x, d1);
            d1 = fmaf(ay[k], b1.y, d1);
            d1 = fmaf(az[k], b1.z, d1);
            mn[k] = fminf(mn[k], fminf(d0, d1));
        }
    }

    // Clamp >=0 so uint bit ordering == float ordering, then combine m-tiles.
#pragma unroll
    for (int k = 0; k < APT; ++k) {
        const int ai = a0 + k * BLOCK + threadIdx.x;
        atomicMin(&outmin[ai], __float_as_uint(fmaxf(mn[k], 0.0f)));
    }
}

__global__ __launch_bounds__(1024) void cd_reduce(const float* __restrict__ wsmin,
                                                  float* __restrict__ out) {
    __shared__ float sred[1024];
    const float4* __restrict__ v = (const float4*)wsmin;
    float s = 0.0f;
    for (int i = threadIdx.x; i < (2 * TOTAL) / 4; i += 1024) {
        float4 x = v[i];
        s += (x.x + x.y) + (x.z + x.w);
    }
    sred[threadIdx.x] = s;
    __syncthreads();
    for (int st = 512; st > 0; st >>= 1) {
        if (threadIdx.x < st) sred[threadIdx.x] += sred[threadIdx.x + st];
        __syncthreads();
    }
    if (threadIdx.x == 0) out[0] = sred[0] * (1.0f / (float)BQ);
}

extern "C" void kernel_launch(void* const* d_in, const int* in_sizes, int n_in,
                              void* d_out, int out_size, void* d_ws, size_t ws_size,
                              hipStream_t stream) {
    const float* p1 = (const float*)d_in[0];
    const float* p2 = (const float*)d_in[1];
    float* out = (float*)d_out;
    unsigned int* wsmin = (unsigned int*)d_ws;   // needs 2*TOTAL*4 = 512 KiB

    // 1) init per-point mins to +inf (ws is not re-poisoned between replays)
    cd_init_ws<<<(2 * TOTAL) / BLOCK, BLOCK, 0, stream>>>(wsmin);

    // 2) both chamfer directions: grid.x = a-tiles * m-tiles, grid.y = direction
    dim3 grid(ATILES * MT, 2, 1);
    cd_min_kernel<<<grid, BLOCK, 0, stream>>>(p1, p2, wsmin);

    // 3) deterministic single-block sum -> scalar / B
    cd_reduce<<<1, 1024, 0, stream>>>((const float*)wsmin, out);
}

// Round 2
// 52.832 us; speedup vs baseline: 1.3590x; 1.3590x over previous
//
#include <hip/hip_runtime.h>

// ChamferDistance  B=16, N=M=4096, D=3, fp32 in/out (scalar out).
#define BQ     16
#define NPTS   4096
#define TOTAL  (BQ * NPTS)        // 65536 points per side
#define BLOCK  256
#define APT    8                  // a-points per thread (in registers)
#define ATILE  (BLOCK * APT)      // 2048 a-points per block
#define NATILE (TOTAL / ATILE)    // 32 a-tiles
#define MTILE  256                // b-points staged in LDS per block
#define MT     (NPTS / MTILE)     // 16 m-tiles
#define NPART  128                // partial sums for two-stage reduce

// ws layout:
//   uint32 ws[0 .. 2*TOTAL)          per-point min bits (dir0 then dir1)
//   float  ws[2*TOTAL .. 2*TOTAL+128) stage-1 partial sums (if ws_size allows)

__global__ __launch_bounds__(BLOCK) void cd_init_ws(unsigned int* __restrict__ ws,
                                                    float* __restrict__ out) {
    int i = blockIdx.x * BLOCK + threadIdx.x;
    ws[i] = 0x7F800000u;  // +inf
    if (i == 0) out[0] = 0.0f;
}

__global__ __launch_bounds__(BLOCK) void cd_min_kernel(
        const float* __restrict__ p1, const float* __restrict__ p2,
        unsigned int* __restrict__ wsmin) {
    const int dir = blockIdx.y;
    const float* __restrict__ Aset = dir ? p2 : p1;   // side kept in registers
    const float* __restrict__ Bset = dir ? p1 : p2;   // side scanned from LDS
    unsigned int* __restrict__ outmin = wsmin + dir * TOTAL;

    const int atile = blockIdx.x / MT;
    const int mtile = blockIdx.x % MT;
    const int a0    = atile * ATILE;          // 4096 % 2048 == 0: no batch crossing
    const int batch = a0 / NPTS;
    const int m0    = batch * NPTS + mtile * MTILE;

    // Stage b-tile as (-2bx, -2by, -2bz, |b|^2); a2 is added after the min.
    __shared__ float4 sb[MTILE];
    {
        const int i = threadIdx.x;            // MTILE == BLOCK
        const float* bp = Bset + (size_t)(m0 + i) * 3;
        float bx = bp[0], by = bp[1], bz = bp[2];
        sb[i] = make_float4(-2.0f * bx, -2.0f * by, -2.0f * bz,
                            fmaf(bx, bx, fmaf(by, by, bz * bz)));
    }
    __syncthreads();

    float ax[APT], ay[APT], az[APT], a2[APT], mn[APT];
#pragma unroll
    for (int k = 0; k < APT; ++k) {
        const int ai = a0 + k * BLOCK + threadIdx.x;
        const float* ap = Aset + (size_t)ai * 3;
        ax[k] = ap[0]; ay[k] = ap[1]; az[k] = ap[2];
        a2[k] = fmaf(ax[k], ax[k], fmaf(ay[k], ay[k], az[k] * az[k]));
        mn[k] = 3.0e38f;
    }

    // Inner loop: per j-step 2 broadcast ds_read_b128 feed 16 pair-evals.
    // Per pair: 3 fma + 1/2 v_min3  ->  3.5 VALU ops/pair.
#pragma unroll 2
    for (int j = 0; j < MTILE; j += 2) {
        const float4 b0 = sb[j];
        const float4 b1 = sb[j + 1];
#pragma unroll
        for (int k = 0; k < APT; ++k) {
            float d0 = fmaf(az[k], b0.z, b0.w);
            d0 = fmaf(ay[k], b0.y, d0);
            d0 = fmaf(ax[k], b0.x, d0);
            float d1 = fmaf(az[k], b1.z, b1.w);
            d1 = fmaf(ay[k], b1.y, d1);
            d1 = fmaf(ax[k], b1.x, d1);
            float m;
            asm("v_min3_f32 %0, %1, %2, %3" : "=v"(m) : "v"(mn[k]), "v"(d0), "v"(d1));
            mn[k] = m;
        }
    }

    // a2 added once per a-point; clamp >=0 so uint ordering == float ordering.
#pragma unroll
    for (int k = 0; k < APT; ++k) {
        const int ai = a0 + k * BLOCK + threadIdx.x;
        atomicMin(&outmin[ai], __float_as_uint(fmaxf(a2[k] + mn[k], 0.0f)));
    }
}

// -------- two-stage deterministic sum --------
__global__ __launch_bounds__(BLOCK) void cd_reduce1(const float* __restrict__ wsmin,
                                                    float* __restrict__ partial) {
    __shared__ float sred[BLOCK];
    const float4* __restrict__ v = (const float4*)wsmin;
    const int i = blockIdx.x * BLOCK + threadIdx.x;     // 128*256 == 2*TOTAL/4
    float4 x = v[i];
    float s = (x.x + x.y) + (x.z + x.w);
    sred[threadIdx.x] = s;
    __syncthreads();
    for (int st = BLOCK / 2; st > 0; st >>= 1) {
        if (threadIdx.x < st) sred[threadIdx.x] += sred[threadIdx.x + st];
        __syncthreads();
    }
    if (threadIdx.x == 0) partial[blockIdx.x] = sred[0];
}

__global__ __launch_bounds__(NPART) void cd_reduce2(const float* __restrict__ partial,
                                                    float* __restrict__ out) {
    __shared__ float sred[NPART];
    sred[threadIdx.x] = partial[threadIdx.x];
    __syncthreads();
    for (int st = NPART / 2; st > 0; st >>= 1) {
        if (threadIdx.x < st) sred[threadIdx.x] += sred[threadIdx.x + st];
        __syncthreads();
    }
    if (threadIdx.x == 0) out[0] = sred[0] * (1.0f / (float)BQ);
}

// fallback: single-block deterministic sum (if ws too small for partials)
__global__ __launch_bounds__(1024) void cd_reduce_single(const float* __restrict__ wsmin,
                                                         float* __restrict__ out) {
    __shared__ float sred[1024];
    const float4* __restrict__ v = (const float4*)wsmin;
    float s = 0.0f;
    for (int i = threadIdx.x; i < (2 * TOTAL) / 4; i += 1024) {
        float4 x = v[i];
        s += (x.x + x.y) + (x.z + x.w);
    }
    sred[threadIdx.x] = s;
    __syncthreads();
    for (int st = 512; st > 0; st >>= 1) {
        if (threadIdx.x < st) sred[threadIdx.x] += sred[threadIdx.x + st];
        __syncthreads();
    }
    if (threadIdx.x == 0) out[0] = sred[0] * (1.0f / (float)BQ);
}

extern "C" void kernel_launch(void* const* d_in, const int* in_sizes, int n_in,
                              void* d_out, int out_size, void* d_ws, size_t ws_size,
                              hipStream_t stream) {
    const float* p1 = (const float*)d_in[0];
    const float* p2 = (const float*)d_in[1];
    float* out = (float*)d_out;
    unsigned int* wsmin = (unsigned int*)d_ws;          // 2*TOTAL*4 = 512 KiB
    float* partial = (float*)((char*)d_ws + (size_t)2 * TOTAL * 4);

    cd_init_ws<<<(2 * TOTAL) / BLOCK, BLOCK, 0, stream>>>(wsmin, out);

    dim3 grid(NATILE * MT, 2, 1);                       // 512 x 2 = 1024 blocks
    cd_min_kernel<<<grid, BLOCK, 0, stream>>>(p1, p2, wsmin);

    if (ws_size >= (size_t)2 * TOTAL * 4 + NPART * 4) {
        cd_reduce1<<<NPART, BLOCK, 0, stream>>>((const float*)wsmin, partial);
        cd_reduce2<<<1, NPART, 0, stream>>>(partial, out);
    } else {
        cd_reduce_single<<<1, 1024, 0, stream>>>((const float*)wsmin, out);
    }
}